// Round 1
// 1299.243 us; speedup vs baseline: 1.3624x; 1.3624x over previous
//
#include <hip/hip_runtime.h>
#include <stdint.h>

static constexpr int BATCH = 16;
static constexpr int Hh = 1024;
static constexpr int Ww = 1024;
static constexpr int HW = Hh * Ww;        // 2^20
static constexpr int NPIX = BATCH * HW;   // 2^24
static constexpr int TS = 32;             // tile side
static constexpr int TPIX = TS * TS;      // 1024 pixels per tile

// ---------------- global union-find (Komura/Playne atomic min-link) --------

// Path-halving find: ONLY safe during the merge phase (k_border), where the
// merge retry loop re-establishes any link displaced by a racing plain store.
__device__ __forceinline__ int find_root_halve(int* parent, int i) {
    while (true) {
        int p = parent[i];
        if (p == i) return i;
        int gp = parent[p];
        if (gp == p) return p;
        parent[i] = gp;        // plain store of an ancestor — merge-phase safe
        i = gp;
    }
}

// Read-only find: used in k_roots. Safe concurrently with k_roots' own
// parent[r]=final stores because those stores only ever write FINAL roots
// (self-terminating), never mid-chain ancestors.
__device__ __forceinline__ int find_root_ro(const int* parent, int i) {
    int p = parent[i];
    while (p != i) { i = p; p = parent[i]; }
    return i;
}

__device__ __forceinline__ void merge_uf(int* parent, int a, int b) {
    while (true) {
        a = find_root_halve(parent, a);
        b = find_root_halve(parent, b);
        if (a == b) return;
        if (a > b) { int t = a; a = b; b = t; }   // ensure a < b
        int old = atomicMin(&parent[b], a);
        if (old == b) return;   // b was a root and we linked it under a
        b = old;                // someone else linked b first; merge with that
    }
}

// ---------------- K1: per-tile local CCL in LDS ----------------------------
// 32x32 tile, 256 threads, 4 px/thread. Resolves all intra-tile connectivity
// in shared memory, writes tile-rooted labels (depth <= 1) to global parent,
// and writes the per-local-root pixel count into counts[root_g].
// counts[i] > 0 afterwards IFF i is an original tile root (free root flag).

__global__ __launch_bounds__(256) void k_local(const float* __restrict__ x,
                                               int* __restrict__ parent,
                                               int* __restrict__ counts,
                                               unsigned long long* __restrict__ best) {
    __shared__ int lab[TPIX];
    __shared__ int cnt[TPIX];

    int tile = blockIdx.x;          // 16 images * 1024 tiles
    int b = tile >> 10;
    int t = tile & 1023;
    int th = t >> 5, tw = t & 31;
    int h0 = th * TS, w0 = tw * TS;
    const float* xb = x + (size_t)b * 2 * (size_t)HW;
    int base = b * HW + h0 * Ww + w0;   // global idx of local (0,0)

    if (tile == 0 && threadIdx.x < BATCH) best[threadIdx.x] = 0ull;

    // init local labels from fg = (x1 > x0)
    #pragma unroll
    for (int k = 0; k < 4; k++) {
        int p = threadIdx.x + k * 256;      // local index
        int lh = p >> 5, lw = p & 31;
        int off = (h0 + lh) * Ww + (w0 + lw);
        float x0 = xb[off];
        float x1 = xb[off + HW];
        lab[p] = (x1 > x0) ? p : -1;
        cnt[p] = 0;
        counts[base + lh * Ww + lw] = 0;    // zero counts along the way
    }
    __syncthreads();

    // LDS union-find merge with 4 "prior" neighbors (W, NW, N, NE)
    auto find_l = [&](int i) {
        int p = lab[i];
        while (p != i) { i = p; p = lab[i]; }
        return i;
    };
    auto merge_l = [&](int a, int c) {
        while (true) {
            a = find_l(a); c = find_l(c);
            if (a == c) return;
            if (a > c) { int tt = a; a = c; c = tt; }
            int old = atomicMin(&lab[c], a);
            if (old == c) return;
            c = old;
        }
    };

    #pragma unroll
    for (int k = 0; k < 4; k++) {
        int p = threadIdx.x + k * 256;
        if (lab[p] < 0) continue;
        int lh = p >> 5, lw = p & 31;
        if (lw > 0 && lab[p - 1] >= 0) merge_l(p, p - 1);
        if (lh > 0) {
            if (lab[p - TS] >= 0) merge_l(p, p - TS);
            if (lw > 0 && lab[p - TS - 1] >= 0) merge_l(p, p - TS - 1);
            if (lw < TS - 1 && lab[p - TS + 1] >= 0) merge_l(p, p - TS + 1);
        }
    }
    __syncthreads();

    // flatten + write global labels + wave-aggregated local component counts
    int lane = threadIdx.x & 63;
    #pragma unroll
    for (int k = 0; k < 4; k++) {
        int p = threadIdx.x + k * 256;
        int lh = p >> 5, lw = p & 31;
        int g = base + lh * Ww + lw;
        int v = lab[p];
        bool need = (v >= 0);
        int r = -1;
        if (need) r = find_l(p);
        parent[g] = need ? (base + (r >> 5) * Ww + (r & 31)) : -1;
        // wave-aggregated LDS count: one LDS atomic per (wave, distinct root)
        while (__any(need)) {
            unsigned long long m = __ballot(need);
            int src = (int)(__ffsll((unsigned long long)m) - 1);
            int rr = __shfl(r, src);
            bool mine = need && (r == rr);
            unsigned long long grp = __ballot(mine);
            if (mine && lane == src) atomicAdd(&cnt[rr], (int)__popcll(grp));
            if (mine) need = false;
        }
    }
    __syncthreads();

    // local roots publish their component size (same thread zeroed this slot
    // in the init loop -> program order guarantees 0-then-count)
    #pragma unroll
    for (int k = 0; k < 4; k++) {
        int p = threadIdx.x + k * 256;
        if (lab[p] == p) {
            int g = base + (p >> 5) * Ww + (p & 31);
            counts[g] = cnt[p];
        }
    }
}

// ---------------- K2: cross-tile border merges (border threads only) -------
// Per batch: group A = rows h%32==0 (32*1024 px), group B = cols w%32 in
// {0,31} (1024*64 px). Corner pixels appear in both groups; merge_uf is
// idempotent so duplicate processing is harmless.

static constexpr int BORDER_A = 32 * 1024;          // 32768
static constexpr int BORDER_PER_B = BORDER_A + 1024 * 64;  // 98304

__global__ __launch_bounds__(256) void k_border(int* __restrict__ parent) {
    int b = blockIdx.y;
    int t = blockIdx.x * blockDim.x + threadIdx.x;
    int h, w;
    if (t < BORDER_A) {
        h = (t >> 10) << 5;             // 0,32,...,992
        w = t & 1023;
    } else {
        int t2 = t - BORDER_A;          // 0..65535
        int c = t2 & 63;                // 64 border columns
        h = t2 >> 6;                    // 0..1023
        w = ((c >> 1) << 5) + ((c & 1) ? (TS - 1) : 0);
    }
    int i = b * HW + h * Ww + w;
    if (parent[i] < 0) return;
    bool hb = (h & 31) == 0;
    bool wb = (w & 31) == 0;
    bool we = (w & 31) == 31;
    if (wb && w > 0 && parent[i - 1] >= 0) merge_uf(parent, i, i - 1);
    if (h > 0) {
        if (hb && parent[i - Ww] >= 0) merge_uf(parent, i, i - Ww);
        if ((hb | wb) && w > 0 && parent[i - Ww - 1] >= 0) merge_uf(parent, i, i - Ww - 1);
        if ((hb | we) && w < Ww - 1 && parent[i - Ww + 1] >= 0) merge_uf(parent, i, i - Ww + 1);
    }
}

// ---------------- K3: root-only compress + hierarchical count fold ---------
// counts[i] > 0 <=> i is an original tile root. Chains pass only through
// tile roots, so compressing these (~0.5M) makes every pixel's root
// reachable in 2 hops. Count folding does one atomic per NON-final tile
// root (giant component: ~a few thousand per batch, vs ~16K/batch wave-
// aggregated pixel atomics before).

__global__ __launch_bounds__(256) void k_roots(int* __restrict__ parent,
                                               int* __restrict__ counts) {
    int i = blockIdx.x * blockDim.x + threadIdx.x;
    int c = counts[i];
    if (c <= 0) return;                      // not an original tile root
    int root = find_root_ro(parent, i);
    if (root != i) {
        parent[i] = root;                    // full compression of root nodes
        atomicAdd(&counts[root], c);         // fold my count into final root
        counts[i] = 0;                       // only final roots keep counts
    }
}

// ---------------- K4: argmax(count), smallest-root tie-break ---------------

__global__ __launch_bounds__(256) void k_argmax(const int* __restrict__ counts,
                                                unsigned long long* __restrict__ best) {
    int i = blockIdx.x * blockDim.x + threadIdx.x;
    int c = counts[i];
    unsigned long long v = 0ull;
    if (c > 0)
        v = (((unsigned long long)(unsigned)c) << 32) |
            (unsigned long long)(0xFFFFFFFFu - (unsigned)i);
    for (int off = 32; off > 0; off >>= 1) {
        unsigned long long o = __shfl_down(v, off);
        if (o > v) v = o;
    }
    if ((threadIdx.x & 63) == 0 && v != 0ull)
        atomicMax(&best[i >> 20], v);
}

// ---------------- K5: apply mask (2-hop root lookup) -----------------------
// parent[i] is some original tile root (possibly i itself); after k_roots
// every tile root points directly at its final root, so root(i) =
// parent[parent[i]] exactly.

__global__ __launch_bounds__(256) void k_final(const float* __restrict__ x,
                                               const int* __restrict__ parent,
                                               const unsigned long long* __restrict__ best,
                                               float* __restrict__ out) {
    int i = blockIdx.x * blockDim.x + threadIdx.x;
    int b = i >> 20;
    int p = i & (HW - 1);
    unsigned long long bv = best[b];
    int broot = (int)(0xFFFFFFFFu - (unsigned)(bv & 0xFFFFFFFFull));
    int pr = parent[i];
    int a = (pr >= 0) ? pr : 0;              // safe dummy index for bg
    int root = parent[a];                    // mostly-broadcast gather
    bool mask = (pr >= 0) && (root == broot);
    const float* xb = x + ((size_t)b * 2) * (size_t)HW;
    float* ob = out + ((size_t)b * 2) * (size_t)HW;
    float x0 = xb[p];
    float x1 = xb[p + HW];
    ob[p]      = mask ? x0 : 0.0f;
    ob[p + HW] = mask ? x1 : 0.0f;
}

// ---------------- launch ---------------------------------------------------

extern "C" void kernel_launch(void* const* d_in, const int* in_sizes, int n_in,
                              void* d_out, int out_size, void* d_ws, size_t ws_size,
                              hipStream_t stream) {
    const float* x = (const float*)d_in[0];
    float* out = (float*)d_out;

    // workspace layout: best[16] u64 (256B pad) | parent[NPIX] i32 | counts[NPIX] i32
    unsigned long long* best = (unsigned long long*)d_ws;
    int* parent = (int*)((char*)d_ws + 256);
    int* counts = parent + NPIX;

    dim3 blk(256);
    dim3 grd(NPIX / 256);
    dim3 grd_tiles(BATCH * (Hh / TS) * (Ww / TS));   // 16384 tiles
    dim3 grd_border(BORDER_PER_B / 256, BATCH);      // 384 x 16 blocks

    k_local  <<<grd_tiles, blk, 0, stream>>>(x, parent, counts, best);
    k_border <<<grd_border, blk, 0, stream>>>(parent);
    k_roots  <<<grd, blk, 0, stream>>>(parent, counts);
    k_argmax <<<grd, blk, 0, stream>>>(counts, best);
    k_final  <<<grd, blk, 0, stream>>>(x, parent, best, out);
}

// Round 2
// 853.054 us; speedup vs baseline: 2.0750x; 1.5230x over previous
//
#include <hip/hip_runtime.h>
#include <stdint.h>

static constexpr int BATCH = 16;
static constexpr int Hh = 1024;
static constexpr int Ww = 1024;
static constexpr int HW = Hh * Ww;        // 2^20
static constexpr int NPIX = BATCH * HW;   // 2^24
static constexpr int TS = 32;             // tile side
static constexpr int TPIX = TS * TS;      // 1024 pixels per tile

// argmax stage-1 geometry: each block reduces CHUNK counts
static constexpr int CHUNK = 1024;
static constexpr int NBLK1 = NPIX / CHUNK;          // 16384 (1024 per batch)
static constexpr int BLK1_PER_B = HW / CHUNK;       // 1024

// ---------------- global union-find (Komura/Playne atomic min-link) --------

// Path-halving find: ONLY safe during the merge phase (k_border), where the
// merge retry loop re-establishes any link displaced by a racing plain store.
__device__ __forceinline__ int find_root_halve(int* parent, int i) {
    while (true) {
        int p = parent[i];
        if (p == i) return i;
        int gp = parent[p];
        if (gp == p) return p;
        parent[i] = gp;        // plain store of an ancestor — merge-phase safe
        i = gp;
    }
}

// Read-only find: used in k_roots. Safe concurrently with k_roots' own
// parent[r]=final stores because those stores only ever write FINAL roots
// (self-terminating), never mid-chain ancestors.
__device__ __forceinline__ int find_root_ro(const int* parent, int i) {
    int p = parent[i];
    while (p != i) { i = p; p = parent[i]; }
    return i;
}

__device__ __forceinline__ void merge_uf(int* parent, int a, int b) {
    while (true) {
        a = find_root_halve(parent, a);
        b = find_root_halve(parent, b);
        if (a == b) return;
        if (a > b) { int t = a; a = b; b = t; }   // ensure a < b
        int old = atomicMin(&parent[b], a);
        if (old == b) return;   // b was a root and we linked it under a
        b = old;                // someone else linked b first; merge with that
    }
}

// ---------------- K1: per-tile local CCL in LDS ----------------------------
// 32x32 tile, 256 threads, 4 px/thread. Resolves all intra-tile connectivity
// in shared memory, writes tile-rooted labels (depth <= 1) to global parent,
// and writes the per-local-root pixel count into counts[root_g].
// counts[i] > 0 afterwards IFF i is an original tile root (free root flag).

__global__ __launch_bounds__(256) void k_local(const float* __restrict__ x,
                                               int* __restrict__ parent,
                                               int* __restrict__ counts,
                                               unsigned long long* __restrict__ best) {
    __shared__ int lab[TPIX];
    __shared__ int cnt[TPIX];

    int tile = blockIdx.x;          // 16 images * 1024 tiles
    int b = tile >> 10;
    int t = tile & 1023;
    int th = t >> 5, tw = t & 31;
    int h0 = th * TS, w0 = tw * TS;
    const float* xb = x + (size_t)b * 2 * (size_t)HW;
    int base = b * HW + h0 * Ww + w0;   // global idx of local (0,0)

    if (tile == 0 && threadIdx.x < BATCH) best[threadIdx.x] = 0ull;

    // init local labels from fg = (x1 > x0)
    #pragma unroll
    for (int k = 0; k < 4; k++) {
        int p = threadIdx.x + k * 256;      // local index
        int lh = p >> 5, lw = p & 31;
        int off = (h0 + lh) * Ww + (w0 + lw);
        float x0 = xb[off];
        float x1 = xb[off + HW];
        lab[p] = (x1 > x0) ? p : -1;
        cnt[p] = 0;
        counts[base + lh * Ww + lw] = 0;    // zero counts along the way
    }
    __syncthreads();

    // LDS union-find merge with 4 "prior" neighbors (W, NW, N, NE)
    auto find_l = [&](int i) {
        int p = lab[i];
        while (p != i) { i = p; p = lab[i]; }
        return i;
    };
    auto merge_l = [&](int a, int c) {
        while (true) {
            a = find_l(a); c = find_l(c);
            if (a == c) return;
            if (a > c) { int tt = a; a = c; c = tt; }
            int old = atomicMin(&lab[c], a);
            if (old == c) return;
            c = old;
        }
    };

    #pragma unroll
    for (int k = 0; k < 4; k++) {
        int p = threadIdx.x + k * 256;
        if (lab[p] < 0) continue;
        int lh = p >> 5, lw = p & 31;
        if (lw > 0 && lab[p - 1] >= 0) merge_l(p, p - 1);
        if (lh > 0) {
            if (lab[p - TS] >= 0) merge_l(p, p - TS);
            if (lw > 0 && lab[p - TS - 1] >= 0) merge_l(p, p - TS - 1);
            if (lw < TS - 1 && lab[p - TS + 1] >= 0) merge_l(p, p - TS + 1);
        }
    }
    __syncthreads();

    // flatten + write global labels + wave-aggregated local component counts
    int lane = threadIdx.x & 63;
    #pragma unroll
    for (int k = 0; k < 4; k++) {
        int p = threadIdx.x + k * 256;
        int lh = p >> 5, lw = p & 31;
        int g = base + lh * Ww + lw;
        int v = lab[p];
        bool need = (v >= 0);
        int r = -1;
        if (need) r = find_l(p);
        parent[g] = need ? (base + (r >> 5) * Ww + (r & 31)) : -1;
        // wave-aggregated LDS count: one LDS atomic per (wave, distinct root)
        while (__any(need)) {
            unsigned long long m = __ballot(need);
            int src = (int)(__ffsll((unsigned long long)m) - 1);
            int rr = __shfl(r, src);
            bool mine = need && (r == rr);
            unsigned long long grp = __ballot(mine);
            if (mine && lane == src) atomicAdd(&cnt[rr], (int)__popcll(grp));
            if (mine) need = false;
        }
    }
    __syncthreads();

    // local roots publish their component size (same thread zeroed this slot
    // in the init loop -> program order guarantees 0-then-count)
    #pragma unroll
    for (int k = 0; k < 4; k++) {
        int p = threadIdx.x + k * 256;
        if (lab[p] == p) {
            int g = base + (p >> 5) * Ww + (p & 31);
            counts[g] = cnt[p];
        }
    }
}

// ---------------- K2: cross-tile border merges (border threads only) -------
// Per batch: group A = rows h%32==0 (32*1024 px), group B = cols w%32 in
// {0,31} (1024*64 px). Corner pixels appear in both groups; merge_uf is
// idempotent so duplicate processing is harmless.

static constexpr int BORDER_A = 32 * 1024;          // 32768
static constexpr int BORDER_PER_B = BORDER_A + 1024 * 64;  // 98304

__global__ __launch_bounds__(256) void k_border(int* __restrict__ parent) {
    int b = blockIdx.y;
    int t = blockIdx.x * blockDim.x + threadIdx.x;
    int h, w;
    if (t < BORDER_A) {
        h = (t >> 10) << 5;             // 0,32,...,992
        w = t & 1023;
    } else {
        int t2 = t - BORDER_A;          // 0..65535
        int c = t2 & 63;                // 64 border columns
        h = t2 >> 6;                    // 0..1023
        w = ((c >> 1) << 5) + ((c & 1) ? (TS - 1) : 0);
    }
    int i = b * HW + h * Ww + w;
    if (parent[i] < 0) return;
    bool hb = (h & 31) == 0;
    bool wb = (w & 31) == 0;
    bool we = (w & 31) == 31;
    if (wb && w > 0 && parent[i - 1] >= 0) merge_uf(parent, i, i - 1);
    if (h > 0) {
        if (hb && parent[i - Ww] >= 0) merge_uf(parent, i, i - Ww);
        if ((hb | wb) && w > 0 && parent[i - Ww - 1] >= 0) merge_uf(parent, i, i - Ww - 1);
        if ((hb | we) && w < Ww - 1 && parent[i - Ww + 1] >= 0) merge_uf(parent, i, i - Ww + 1);
    }
}

// ---------------- K3: root-only compress + hierarchical count fold ---------
// counts[i] > 0 <=> i is an original tile root. Chains pass only through
// tile roots, so compressing these (~0.5M) makes every pixel's root
// reachable in 2 hops. Count folding does one atomic per NON-final tile
// root; fold targets are scattered (one line per final root) so they
// parallelize across batches/components.

__global__ __launch_bounds__(256) void k_roots(int* __restrict__ parent,
                                               int* __restrict__ counts) {
    int i = blockIdx.x * blockDim.x + threadIdx.x;
    int c = counts[i];
    if (c <= 0) return;                      // not an original tile root
    int root = find_root_ro(parent, i);
    if (root != i) {
        parent[i] = root;                    // full compression of root nodes
        atomicAdd(&counts[root], c);         // fold my count into final root
        counts[i] = 0;                       // only final roots keep counts
    }
}

// ---------------- K4a: per-block argmax (NO atomics) -----------------------
// Each block reduces CHUNK=1024 consecutive counts (4/thread, coalesced) to
// one packed (count<<32 | ~index) candidate, plain-stored to blockmax.
// Blocks never straddle a batch (HW % CHUNK == 0).

__global__ __launch_bounds__(256) void k_argmax1(const int* __restrict__ counts,
                                                 unsigned long long* __restrict__ blockmax) {
    int base = blockIdx.x * CHUNK;
    unsigned long long v = 0ull;
    #pragma unroll
    for (int k = 0; k < 4; k++) {
        int i = base + threadIdx.x + k * 256;
        int c = counts[i];
        if (c > 0) {
            unsigned long long o =
                (((unsigned long long)(unsigned)c) << 32) |
                (unsigned long long)(0xFFFFFFFFu - (unsigned)i);
            if (o > v) v = o;
        }
    }
    for (int off = 32; off > 0; off >>= 1) {
        unsigned long long o = __shfl_down(v, off);
        if (o > v) v = o;
    }
    __shared__ unsigned long long sm[4];
    if ((threadIdx.x & 63) == 0) sm[threadIdx.x >> 6] = v;
    __syncthreads();
    if (threadIdx.x == 0) {
        v = sm[0];
        #pragma unroll
        for (int w = 1; w < 4; w++) if (sm[w] > v) v = sm[w];
        blockmax[blockIdx.x] = v;            // plain coalesced store
    }
}

// ---------------- K4b: per-batch final argmax (NO atomics) -----------------

__global__ __launch_bounds__(256) void k_argmax2(const unsigned long long* __restrict__ blockmax,
                                                 unsigned long long* __restrict__ best) {
    int b = blockIdx.x;
    const unsigned long long* src = blockmax + b * BLK1_PER_B;
    unsigned long long v = 0ull;
    #pragma unroll
    for (int k = 0; k < BLK1_PER_B / 256; k++) {
        unsigned long long o = src[threadIdx.x + k * 256];
        if (o > v) v = o;
    }
    for (int off = 32; off > 0; off >>= 1) {
        unsigned long long o = __shfl_down(v, off);
        if (o > v) v = o;
    }
    __shared__ unsigned long long sm[4];
    if ((threadIdx.x & 63) == 0) sm[threadIdx.x >> 6] = v;
    __syncthreads();
    if (threadIdx.x == 0) {
        v = sm[0];
        #pragma unroll
        for (int w = 1; w < 4; w++) if (sm[w] > v) v = sm[w];
        best[b] = v;                         // plain store, one per batch
    }
}

// ---------------- K5: apply mask (2-hop root lookup) -----------------------
// parent[i] is some original tile root (possibly i itself); after k_roots
// every tile root points directly at its final root, so root(i) =
// parent[parent[i]] exactly.

__global__ __launch_bounds__(256) void k_final(const float* __restrict__ x,
                                               const int* __restrict__ parent,
                                               const unsigned long long* __restrict__ best,
                                               float* __restrict__ out) {
    int i = blockIdx.x * blockDim.x + threadIdx.x;
    int b = i >> 20;
    int p = i & (HW - 1);
    unsigned long long bv = best[b];
    int broot = (int)(0xFFFFFFFFu - (unsigned)(bv & 0xFFFFFFFFull));
    int pr = parent[i];
    int a = (pr >= 0) ? pr : 0;              // safe dummy index for bg
    int root = parent[a];                    // mostly-broadcast gather
    bool mask = (pr >= 0) && (root == broot);
    const float* xb = x + ((size_t)b * 2) * (size_t)HW;
    float* ob = out + ((size_t)b * 2) * (size_t)HW;
    float x0 = xb[p];
    float x1 = xb[p + HW];
    ob[p]      = mask ? x0 : 0.0f;
    ob[p + HW] = mask ? x1 : 0.0f;
}

// ---------------- launch ---------------------------------------------------

extern "C" void kernel_launch(void* const* d_in, const int* in_sizes, int n_in,
                              void* d_out, int out_size, void* d_ws, size_t ws_size,
                              hipStream_t stream) {
    const float* x = (const float*)d_in[0];
    float* out = (float*)d_out;

    // workspace layout:
    //   best[16] u64 (256B pad) | parent[NPIX] i32 | counts[NPIX] i32 |
    //   blockmax[NBLK1] u64 (128KB)
    unsigned long long* best = (unsigned long long*)d_ws;
    int* parent = (int*)((char*)d_ws + 256);
    int* counts = parent + NPIX;
    unsigned long long* blockmax = (unsigned long long*)(counts + NPIX);

    dim3 blk(256);
    dim3 grd(NPIX / 256);
    dim3 grd_tiles(BATCH * (Hh / TS) * (Ww / TS));   // 16384 tiles
    dim3 grd_border(BORDER_PER_B / 256, BATCH);      // 384 x 16 blocks

    k_local   <<<grd_tiles, blk, 0, stream>>>(x, parent, counts, best);
    k_border  <<<grd_border, blk, 0, stream>>>(parent);
    k_roots   <<<grd, blk, 0, stream>>>(parent, counts);
    k_argmax1 <<<dim3(NBLK1), blk, 0, stream>>>(counts, blockmax);
    k_argmax2 <<<dim3(BATCH), blk, 0, stream>>>(blockmax, best);
    k_final   <<<grd, blk, 0, stream>>>(x, parent, best, out);
}

// Round 3
// 659.275 us; speedup vs baseline: 2.6849x; 1.2939x over previous
//
#include <hip/hip_runtime.h>
#include <stdint.h>

static constexpr int BATCH = 16;
static constexpr int Hh = 1024;
static constexpr int Ww = 1024;
static constexpr int HW = Hh * Ww;        // 2^20
static constexpr int NPIX = BATCH * HW;   // 2^24
static constexpr int TS = 64;             // tile side (64x64 local CCL)
static constexpr int TPIX = TS * TS;      // 4096 pixels per tile
static constexpr int TILES_PER_IMG = (Hh / TS) * (Ww / TS);   // 256

// argmax stage-1 geometry: each block reduces CHUNK counts
static constexpr int CHUNK = 1024;
static constexpr int NBLK1 = NPIX / CHUNK;          // 16384 (1024 per batch)
static constexpr int BLK1_PER_B = HW / CHUNK;       // 1024

// ---------------- global union-find (Komura/Playne atomic min-link) --------

// Path-halving find: ONLY safe during the merge phase (k_border), where the
// merge retry loop re-establishes any link displaced by a racing plain store.
__device__ __forceinline__ int find_root_halve(int* parent, int i) {
    while (true) {
        int p = parent[i];
        if (p == i) return i;
        int gp = parent[p];
        if (gp == p) return p;
        parent[i] = gp;        // plain store of an ancestor — merge-phase safe
        i = gp;
    }
}

// Read-only find: used in k_roots. Safe concurrently with k_roots' own
// parent[r]=final stores because those stores only ever write FINAL roots
// (self-terminating), never mid-chain ancestors.
__device__ __forceinline__ int find_root_ro(const int* parent, int i) {
    int p = parent[i];
    while (p != i) { i = p; p = parent[i]; }
    return i;
}

__device__ __forceinline__ void merge_uf(int* parent, int a, int b) {
    while (true) {
        a = find_root_halve(parent, a);
        b = find_root_halve(parent, b);
        if (a == b) return;
        if (a > b) { int t = a; a = b; b = t; }   // ensure a < b
        int old = atomicMin(&parent[b], a);
        if (old == b) return;   // b was a root and we linked it under a
        b = old;                // someone else linked b first; merge with that
    }
}

// ---------------- K1: per-tile local CCL in LDS ----------------------------
// 64x64 tile, 256 threads, 16 px/thread. Resolves all intra-tile connectivity
// in shared memory, writes tile-rooted labels (depth <= 1) to global parent,
// and writes the per-local-root pixel count into counts[root_g].
// counts[i] > 0 afterwards IFF i is an original tile root (free root flag).

__global__ __launch_bounds__(256) void k_local(const float* __restrict__ x,
                                               int* __restrict__ parent,
                                               int* __restrict__ counts,
                                               unsigned long long* __restrict__ best) {
    __shared__ int lab[TPIX];
    __shared__ int cnt[TPIX];

    int tile = blockIdx.x;          // 16 images * 256 tiles
    int b = tile >> 8;
    int t = tile & 255;
    int th = t >> 4, tw = t & 15;
    int h0 = th * TS, w0 = tw * TS;
    const float* xb = x + (size_t)b * 2 * (size_t)HW;
    int base = b * HW + h0 * Ww + w0;   // global idx of local (0,0)

    if (tile == 0 && threadIdx.x < BATCH) best[threadIdx.x] = 0ull;

    // init local labels from fg = (x1 > x0)
    #pragma unroll
    for (int k = 0; k < TPIX / 256; k++) {
        int p = threadIdx.x + k * 256;      // local index
        int lh = p >> 6, lw = p & 63;
        int off = (h0 + lh) * Ww + (w0 + lw);
        float x0 = xb[off];
        float x1 = xb[off + HW];
        lab[p] = (x1 > x0) ? p : -1;
        cnt[p] = 0;
        counts[base + lh * Ww + lw] = 0;    // zero counts along the way
    }
    __syncthreads();

    // LDS union-find. Merge-phase find uses path halving (retry loop makes
    // racing ancestor stores safe, same argument as find_root_halve).
    auto find_lh = [&](int i) {
        while (true) {
            int p = lab[i];
            if (p == i) return i;
            int gp = lab[p];
            if (gp == p) return p;
            lab[i] = gp;
            i = gp;
        }
    };
    auto merge_l = [&](int a, int c) {
        while (true) {
            a = find_lh(a); c = find_lh(c);
            if (a == c) return;
            if (a > c) { int tt = a; a = c; c = tt; }
            int old = atomicMin(&lab[c], a);
            if (old == c) return;
            c = old;
        }
    };

    #pragma unroll
    for (int k = 0; k < TPIX / 256; k++) {
        int p = threadIdx.x + k * 256;
        if (lab[p] < 0) continue;
        int lh = p >> 6, lw = p & 63;
        if (lw > 0 && lab[p - 1] >= 0) merge_l(p, p - 1);
        if (lh > 0) {
            if (lab[p - TS] >= 0) merge_l(p, p - TS);
            if (lw > 0 && lab[p - TS - 1] >= 0) merge_l(p, p - TS - 1);
            if (lw < TS - 1 && lab[p - TS + 1] >= 0) merge_l(p, p - TS + 1);
        }
    }
    __syncthreads();

    // flatten + write global labels + wave-aggregated local component counts
    // (tree is static now; read-only walk)
    auto find_ro = [&](int i) {
        int p = lab[i];
        while (p != i) { i = p; p = lab[i]; }
        return i;
    };
    int lane = threadIdx.x & 63;
    #pragma unroll
    for (int k = 0; k < TPIX / 256; k++) {
        int p = threadIdx.x + k * 256;
        int lh = p >> 6, lw = p & 63;
        int g = base + lh * Ww + lw;
        int v = lab[p];
        bool need = (v >= 0);
        int r = -1;
        if (need) r = find_ro(p);
        parent[g] = need ? (base + (r >> 6) * Ww + (r & 63)) : -1;
        // wave-aggregated LDS count: one LDS atomic per (wave, distinct root)
        while (__any(need)) {
            unsigned long long m = __ballot(need);
            int src = (int)(__ffsll((unsigned long long)m) - 1);
            int rr = __shfl(r, src);
            bool mine = need && (r == rr);
            unsigned long long grp = __ballot(mine);
            if (mine && lane == src) atomicAdd(&cnt[rr], (int)__popcll(grp));
            if (mine) need = false;
        }
    }
    __syncthreads();

    // local roots publish their component size (same thread zeroed this slot
    // in the init loop -> program order guarantees 0-then-count)
    #pragma unroll
    for (int k = 0; k < TPIX / 256; k++) {
        int p = threadIdx.x + k * 256;
        if (lab[p] == p) {
            int g = base + (p >> 6) * Ww + (p & 63);
            counts[g] = cnt[p];
        }
    }
}

// ---------------- K2: cross-tile border merges (border threads only) -------
// Per batch: group A = rows h%64==0 (16*1024 px), group B = cols w%64 in
// {0,63} (1024*32 px). Corner pixels appear in both groups; merge_uf is
// idempotent so duplicate processing is harmless.

static constexpr int BORDER_A = (Hh / TS) * Ww;                 // 16384
static constexpr int BORDER_PER_B = BORDER_A + Hh * (Ww / TS) * 2;  // 49152

__global__ __launch_bounds__(256) void k_border(int* __restrict__ parent) {
    int b = blockIdx.y;
    int t = blockIdx.x * blockDim.x + threadIdx.x;
    int h, w;
    if (t < BORDER_A) {
        h = (t >> 10) << 6;             // 0,64,...,960
        w = t & 1023;
    } else {
        int t2 = t - BORDER_A;          // 0..32767
        int c = t2 & 31;                // 32 border columns (16 tiles x 2 edges)
        h = t2 >> 5;                    // 0..1023
        w = ((c >> 1) << 6) + ((c & 1) ? (TS - 1) : 0);
    }
    int i = b * HW + h * Ww + w;
    if (parent[i] < 0) return;
    bool hb = (h & (TS - 1)) == 0;
    bool wb = (w & (TS - 1)) == 0;
    bool we = (w & (TS - 1)) == (TS - 1);
    if (wb && w > 0 && parent[i - 1] >= 0) merge_uf(parent, i, i - 1);
    if (h > 0) {
        if (hb && parent[i - Ww] >= 0) merge_uf(parent, i, i - Ww);
        if ((hb | wb) && w > 0 && parent[i - Ww - 1] >= 0) merge_uf(parent, i, i - Ww - 1);
        if ((hb | we) && w < Ww - 1 && parent[i - Ww + 1] >= 0) merge_uf(parent, i, i - Ww + 1);
    }
}

// ---------------- K3: root-only compress + hierarchical count fold ---------
// counts[i] > 0 <=> i is an original tile root. Chains pass only through
// tile roots, so compressing these makes every pixel's root reachable in
// 2 hops. Count folding does one atomic per NON-final tile root; fold
// targets are scattered so they parallelize across batches/components.

__global__ __launch_bounds__(256) void k_roots(int* __restrict__ parent,
                                               int* __restrict__ counts) {
    int i = blockIdx.x * blockDim.x + threadIdx.x;
    int c = counts[i];
    if (c <= 0) return;                      // not an original tile root
    int root = find_root_ro(parent, i);
    if (root != i) {
        parent[i] = root;                    // full compression of root nodes
        atomicAdd(&counts[root], c);         // fold my count into final root
        counts[i] = 0;                       // only final roots keep counts
    }
}

// ---------------- K4a: per-block argmax (NO atomics) -----------------------
// Each block reduces CHUNK=1024 consecutive counts (4/thread, coalesced) to
// one packed (count<<32 | ~index) candidate, plain-stored to blockmax.
// Blocks never straddle a batch (HW % CHUNK == 0).

__global__ __launch_bounds__(256) void k_argmax1(const int* __restrict__ counts,
                                                 unsigned long long* __restrict__ blockmax) {
    int base = blockIdx.x * CHUNK;
    unsigned long long v = 0ull;
    #pragma unroll
    for (int k = 0; k < 4; k++) {
        int i = base + threadIdx.x + k * 256;
        int c = counts[i];
        if (c > 0) {
            unsigned long long o =
                (((unsigned long long)(unsigned)c) << 32) |
                (unsigned long long)(0xFFFFFFFFu - (unsigned)i);
            if (o > v) v = o;
        }
    }
    for (int off = 32; off > 0; off >>= 1) {
        unsigned long long o = __shfl_down(v, off);
        if (o > v) v = o;
    }
    __shared__ unsigned long long sm[4];
    if ((threadIdx.x & 63) == 0) sm[threadIdx.x >> 6] = v;
    __syncthreads();
    if (threadIdx.x == 0) {
        v = sm[0];
        #pragma unroll
        for (int w = 1; w < 4; w++) if (sm[w] > v) v = sm[w];
        blockmax[blockIdx.x] = v;            // plain coalesced store
    }
}

// ---------------- K4b: per-batch final argmax (NO atomics) -----------------

__global__ __launch_bounds__(256) void k_argmax2(const unsigned long long* __restrict__ blockmax,
                                                 unsigned long long* __restrict__ best) {
    int b = blockIdx.x;
    const unsigned long long* src = blockmax + b * BLK1_PER_B;
    unsigned long long v = 0ull;
    #pragma unroll
    for (int k = 0; k < BLK1_PER_B / 256; k++) {
        unsigned long long o = src[threadIdx.x + k * 256];
        if (o > v) v = o;
    }
    for (int off = 32; off > 0; off >>= 1) {
        unsigned long long o = __shfl_down(v, off);
        if (o > v) v = o;
    }
    __shared__ unsigned long long sm[4];
    if ((threadIdx.x & 63) == 0) sm[threadIdx.x >> 6] = v;
    __syncthreads();
    if (threadIdx.x == 0) {
        v = sm[0];
        #pragma unroll
        for (int w = 1; w < 4; w++) if (sm[w] > v) v = sm[w];
        best[b] = v;                         // plain store, one per batch
    }
}

// ---------------- K5: apply mask (2-hop root lookup) -----------------------
// parent[i] is some original tile root (possibly i itself); after k_roots
// every tile root points directly at its final root, so root(i) =
// parent[parent[i]] exactly.

__global__ __launch_bounds__(256) void k_final(const float* __restrict__ x,
                                               const int* __restrict__ parent,
                                               const unsigned long long* __restrict__ best,
                                               float* __restrict__ out) {
    int i = blockIdx.x * blockDim.x + threadIdx.x;
    int b = i >> 20;
    int p = i & (HW - 1);
    unsigned long long bv = best[b];
    int broot = (int)(0xFFFFFFFFu - (unsigned)(bv & 0xFFFFFFFFull));
    int pr = parent[i];
    int a = (pr >= 0) ? pr : 0;              // safe dummy index for bg
    int root = parent[a];                    // mostly-broadcast gather
    bool mask = (pr >= 0) && (root == broot);
    const float* xb = x + ((size_t)b * 2) * (size_t)HW;
    float* ob = out + ((size_t)b * 2) * (size_t)HW;
    float x0 = xb[p];
    float x1 = xb[p + HW];
    ob[p]      = mask ? x0 : 0.0f;
    ob[p + HW] = mask ? x1 : 0.0f;
}

// ---------------- launch ---------------------------------------------------

extern "C" void kernel_launch(void* const* d_in, const int* in_sizes, int n_in,
                              void* d_out, int out_size, void* d_ws, size_t ws_size,
                              hipStream_t stream) {
    const float* x = (const float*)d_in[0];
    float* out = (float*)d_out;

    // workspace layout:
    //   best[16] u64 (256B pad) | parent[NPIX] i32 | counts[NPIX] i32 |
    //   blockmax[NBLK1] u64 (128KB)
    unsigned long long* best = (unsigned long long*)d_ws;
    int* parent = (int*)((char*)d_ws + 256);
    int* counts = parent + NPIX;
    unsigned long long* blockmax = (unsigned long long*)(counts + NPIX);

    dim3 blk(256);
    dim3 grd(NPIX / 256);
    dim3 grd_tiles(BATCH * TILES_PER_IMG);           // 4096 tiles
    dim3 grd_border(BORDER_PER_B / 256, BATCH);      // 192 x 16 blocks

    k_local   <<<grd_tiles, blk, 0, stream>>>(x, parent, counts, best);
    k_border  <<<grd_border, blk, 0, stream>>>(parent);
    k_roots   <<<grd, blk, 0, stream>>>(parent, counts);
    k_argmax1 <<<dim3(NBLK1), blk, 0, stream>>>(counts, blockmax);
    k_argmax2 <<<dim3(BATCH), blk, 0, stream>>>(blockmax, best);
    k_final   <<<grd, blk, 0, stream>>>(x, parent, best, out);
}